// Round 1
// baseline (68.528 us; speedup 1.0000x reference)
//
#include <hip/hip_runtime.h>
#include <hip/hip_bf16.h>
#include <stdint.h>

#define N_CLOTH     16384
#define N_OBS_VERTS 8192
#define N_OBS_FACES 16384

#define NN_CHUNK 512                       // faces per chunk (LDS tile = 8KB)
#define NN_C     (N_OBS_FACES / NN_CHUNK)  // 32 chunks
#define NN_VPT   4                         // vertices per thread
#define NN_TB    256                       // threads per block
#define NN_VBLK  (N_CLOTH / (NN_TB * NN_VPT)) // 16 vertex-blocks

// ---------------------------------------------------------------------------
// K1: per-face precompute.
//   faceA[f]   = (prev_cx, prev_cy, prev_cz, 0.5*||prev_c||^2)
//   facePos[f] = (cur_cx, cur_cy, cur_cz, 0)
//   faceN[f]   = (nx, ny, nz, 0)   unit normal of current triangle
// Also inits keys[] when the atomic fallback path is used.
// ---------------------------------------------------------------------------
__global__ __launch_bounds__(256) void k_faces(
    const float* __restrict__ obs_pos, const float* __restrict__ obs_prev,
    const int* __restrict__ faces,
    float4* __restrict__ faceA, float4* __restrict__ facePos,
    float4* __restrict__ faceN,
    unsigned long long* __restrict__ keys, int initKeys)
{
    int f = blockIdx.x * blockDim.x + threadIdx.x;
    if (f >= N_OBS_FACES) return;

    int i0 = faces[3 * f + 0];
    int i1 = faces[3 * f + 1];
    int i2 = faces[3 * f + 2];

    // previous positions -> prev center + 0.5*norm2
    float ax = obs_prev[3 * i0 + 0], ay = obs_prev[3 * i0 + 1], az = obs_prev[3 * i0 + 2];
    float bx = obs_prev[3 * i1 + 0], by = obs_prev[3 * i1 + 1], bz = obs_prev[3 * i1 + 2];
    float cx = obs_prev[3 * i2 + 0], cy = obs_prev[3 * i2 + 1], cz = obs_prev[3 * i2 + 2];
    float pcx = (ax + bx + cx) * (1.0f / 3.0f);
    float pcy = (ay + by + cy) * (1.0f / 3.0f);
    float pcz = (az + bz + cz) * (1.0f / 3.0f);
    float b2h = 0.5f * (pcx * pcx + pcy * pcy + pcz * pcz);
    faceA[f] = make_float4(pcx, pcy, pcz, b2h);

    // current positions -> cur center + normal
    float ux = obs_pos[3 * i0 + 0], uy = obs_pos[3 * i0 + 1], uz = obs_pos[3 * i0 + 2];
    float vx = obs_pos[3 * i1 + 0], vy = obs_pos[3 * i1 + 1], vz = obs_pos[3 * i1 + 2];
    float wx = obs_pos[3 * i2 + 0], wy = obs_pos[3 * i2 + 1], wz = obs_pos[3 * i2 + 2];
    facePos[f] = make_float4((ux + vx + wx) * (1.0f / 3.0f),
                             (uy + vy + wy) * (1.0f / 3.0f),
                             (uz + vz + wz) * (1.0f / 3.0f), 0.0f);

    float e1x = vx - ux, e1y = vy - uy, e1z = vz - uz;
    float e2x = wx - ux, e2y = wy - uy, e2z = wz - uz;
    float nx = e1y * e2z - e1z * e2y;
    float ny = e1z * e2x - e1x * e2z;
    float nz = e1x * e2y - e1y * e2x;
    float nrm = sqrtf(nx * nx + ny * ny + nz * nz);
    float inv = 1.0f / fmaxf(nrm, 1e-12f);
    faceN[f] = make_float4(nx * inv, ny * inv, nz * inv, 0.0f);

    if (initKeys) keys[f] = 0xFFFFFFFFFFFFFFFFull;  // N_CLOTH == N_OBS_FACES
}

// ---------------------------------------------------------------------------
// K2: 1-NN over one face chunk for NN_VPT vertices per thread.
// key = (monotone_map(float bits of (0.5||b||^2 - a.b)) << 32) | face_idx
// argmin of that key == argmin of d2 with lowest-index tie-break.
// ---------------------------------------------------------------------------
__global__ __launch_bounds__(NN_TB) void k_nn(
    const float* __restrict__ cloth_prev,
    const float4* __restrict__ faceA,
    unsigned long long* __restrict__ out,  // partials [NN_C][N_CLOTH] or keys[N_CLOTH]
    int atomicMode)
{
    __shared__ float4 tile[NN_CHUNK];
    const int t = threadIdx.x;
    const int bv = blockIdx.x;     // vertex block  0..NN_VBLK-1
    const int c = blockIdx.y;      // face chunk    0..NN_C-1
    const int fbase = c * NN_CHUNK;

    for (int i = t; i < NN_CHUNK; i += NN_TB) tile[i] = faceA[fbase + i];

    float vx[NN_VPT], vy[NN_VPT], vz[NN_VPT], best[NN_VPT];
    int bidx[NN_VPT];
#pragma unroll
    for (int j = 0; j < NN_VPT; ++j) {
        int n = bv * (NN_TB * NN_VPT) + j * NN_TB + t;
        vx[j] = cloth_prev[3 * n + 0];
        vy[j] = cloth_prev[3 * n + 1];
        vz[j] = cloth_prev[3 * n + 2];
        best[j] = 3.4e38f;
        bidx[j] = 0;
    }
    __syncthreads();

#pragma unroll 4
    for (int f = 0; f < NN_CHUNK; ++f) {
        float4 b = tile[f];
#pragma unroll
        for (int j = 0; j < NN_VPT; ++j) {
            float s = fmaf(-vx[j], b.x, b.w);
            s = fmaf(-vy[j], b.y, s);
            s = fmaf(-vz[j], b.z, s);
            bool lt = s < best[j];
            bidx[j] = lt ? f : bidx[j];
            best[j] = fminf(s, best[j]);
        }
    }

#pragma unroll
    for (int j = 0; j < NN_VPT; ++j) {
        int n = bv * (NN_TB * NN_VPT) + j * NN_TB + t;
        unsigned int ub = __float_as_uint(best[j]);
        ub = (ub & 0x80000000u) ? ~ub : (ub | 0x80000000u);  // monotone map (handles s<0)
        unsigned long long key =
            ((unsigned long long)ub << 32) | (unsigned int)(fbase + bidx[j]);
        if (atomicMode) atomicMin(&out[n], key);
        else out[(size_t)c * N_CLOTH + n] = key;
    }
}

// ---------------------------------------------------------------------------
// K3: reduce chunk keys per vertex, gather face data, cubic penalty,
// block-sum -> lossPartial[block]
// ---------------------------------------------------------------------------
__global__ __launch_bounds__(256) void k_loss(
    const float* __restrict__ cloth_pred,
    const float4* __restrict__ facePos,
    const float4* __restrict__ faceN,
    const unsigned long long* __restrict__ partials,  // [C][N] (C=1 for atomic path)
    int C,
    float* __restrict__ lossPartial)
{
    const int t = threadIdx.x;
    const int n = blockIdx.x * blockDim.x + t;

    unsigned long long k = partials[n];
    for (int c = 1; c < C; ++c) {
        unsigned long long v = partials[(size_t)c * N_CLOTH + n];
        k = (v < k) ? v : k;
    }
    int idx = (int)(unsigned int)(k & 0xFFFFFFFFull);

    float4 fp = facePos[idx];
    float4 fn = faceN[idx];
    float px = cloth_pred[3 * n + 0];
    float py = cloth_pred[3 * n + 1];
    float pz = cloth_pred[3 * n + 2];
    float d = (px - fp.x) * fn.x + (py - fp.y) * fn.y + (pz - fp.z) * fn.z;
    float tt = fmaxf(1e-3f - d, 0.0f);
    float val = tt * tt * tt;

    __shared__ float red[256];
    red[t] = val;
    __syncthreads();
    for (int s = 128; s > 0; s >>= 1) {
        if (t < s) red[t] += red[t + s];
        __syncthreads();
    }
    if (t == 0) lossPartial[blockIdx.x] = red[0];
}

// ---------------------------------------------------------------------------
// K4: final 64-partial sum * weight(iteration) -> d_out[0]
// ---------------------------------------------------------------------------
__global__ __launch_bounds__(64) void k_final(
    const float* __restrict__ lossPartial,
    const int* __restrict__ iteration,
    float* __restrict__ out)
{
    int t = threadIdx.x;
    float v = lossPartial[t];
#pragma unroll
    for (int o = 32; o > 0; o >>= 1) v += __shfl_down(v, o);
    if (t == 0) {
        int it = iteration[0];
        float itf = (float)(it - 50000);
        itf = fmaxf(itf, 0.0f);
        float prog = fminf(itf * (1.0f / 100000.0f), 1.0f);
        float w = 1.0f + (5000.0f - 1.0f) * prog;
        out[0] = v * w;
    }
}

extern "C" void kernel_launch(void* const* d_in, const int* in_sizes, int n_in,
                              void* d_out, int out_size, void* d_ws, size_t ws_size,
                              hipStream_t stream) {
    const float* obs_pos    = (const float*)d_in[0];
    const float* obs_prev   = (const float*)d_in[1];
    const int*   faces      = (const int*)d_in[2];
    const float* cloth_prev = (const float*)d_in[3];
    const float* cloth_pred = (const float*)d_in[4];
    const int*   iteration  = (const int*)d_in[5];
    float* out = (float*)d_out;

    char* ws = (char*)d_ws;
    float4* faceA   = (float4*)(ws);                         // 256 KB
    float4* facePos = (float4*)(ws + 262144);                // 256 KB
    float4* faceN   = (float4*)(ws + 524288);                // 256 KB
    float*  lossPartial = (float*)(ws + 786432);             // 1 KB (64 used)
    unsigned long long* keys     = (unsigned long long*)(ws + 787456);   // 128 KB
    unsigned long long* partials = (unsigned long long*)(ws + 918528);   // 4 MB

    const size_t need_partials =
        918528ull + (size_t)NN_C * N_CLOTH * sizeof(unsigned long long);
    const bool useAtomic = ws_size < need_partials;

    k_faces<<<N_OBS_FACES / 256, 256, 0, stream>>>(
        obs_pos, obs_prev, faces, faceA, facePos, faceN, keys, useAtomic ? 1 : 0);

    if (useAtomic) {
        k_nn<<<dim3(NN_VBLK, NN_C), NN_TB, 0, stream>>>(cloth_prev, faceA, keys, 1);
        k_loss<<<N_CLOTH / 256, 256, 0, stream>>>(cloth_pred, facePos, faceN,
                                                  keys, 1, lossPartial);
    } else {
        k_nn<<<dim3(NN_VBLK, NN_C), NN_TB, 0, stream>>>(cloth_prev, faceA, partials, 0);
        k_loss<<<N_CLOTH / 256, 256, 0, stream>>>(cloth_pred, facePos, faceN,
                                                  partials, NN_C, lossPartial);
    }
    k_final<<<1, 64, 0, stream>>>(lossPartial, iteration, out);
}